// Round 4
// baseline (3572.955 us; speedup 1.0000x reference)
//
#include <hip/hip_runtime.h>
#include <stdint.h>

#define HCH 256     // H
#define INCH 128    // IN
#define WDIM 512    // WD
#define NRANK 10
#define SLOPE 0.01f

#define BM 128
#define BN 64
#define BK 16
#define PADA 4
#define PADB 4

__device__ __forceinline__ float b2f(ushort u) {
  union { uint32_t i; float f; } x; x.i = ((uint32_t)u) << 16; return x.f;
}
__device__ __forceinline__ ushort f2b(float f) {
  union { float f; uint32_t i; } x; x.f = f;
  uint32_t u = x.i;
  return (ushort)((u + 0x7fffu + ((u >> 16) & 1u)) >> 16);
}
// dual-dtype input read: isbf ? bf16[i] : f32[i]
__device__ __forceinline__ float ldin(const void* p, size_t i, int isbf) {
  return isbf ? b2f(((const ushort*)p)[i]) : ((const float*)p)[i];
}
__device__ __forceinline__ float leaky(float v) { return v >= 0.f ? v : SLOPE * v; }

// ---------------------------------------------------------------------------
// Detect input dtype from w's bit patterns. bf16 N(0,1): every halfword has a
// sane exponent. fp32: low halves are random mantissa bits -> wild exponents.
__global__ void k_detect(const void* __restrict__ w, int* __restrict__ flag) {
  if (threadIdx.x == 0 && blockIdx.x == 0) {
    const ushort* p = (const ushort*)w;
    int bad = 0;
    for (int i = 0; i < 128; i++) {
      ushort u = p[i];
      int e = (u >> 7) & 0xff;
      int z = (u & 0x7fff) == 0;
      if (!z && (e < 96 || e > 134)) bad++;
    }
    flag[0] = (bad == 0) ? 1 : 0;  // 1 = bf16 inputs, 0 = fp32 inputs
  }
}

// ---------------------------------------------------------------------------
// styles[s*5120 + r] = dot(aw_s[r,:512], w) + ab_s[r]   (one wave per row)
__global__ void k_styles(const void* __restrict__ aw0, const void* __restrict__ ab0,
                         const void* __restrict__ aw1, const void* __restrict__ ab1,
                         const void* __restrict__ aw2, const void* __restrict__ ab2,
                         const void* __restrict__ w, float* __restrict__ styles,
                         const int* __restrict__ flag) {
  int wid = blockIdx.x * 4 + (threadIdx.x >> 6);   // 15360 waves
  int lane = threadIdx.x & 63;
  int isbf = flag[0];
  int s = wid / 5120;
  int r = wid - s * 5120;
  const void* aw = (s == 0) ? aw0 : (s == 1) ? aw1 : aw2;
  const void* ab = (s == 0) ? ab0 : (s == 1) ? ab1 : ab2;
  float sum = 0.f;
#pragma unroll
  for (int j = 0; j < 8; j++) {
    int kk = j * 64 + lane;
    sum += ldin(aw, (size_t)r * WDIM + kk, isbf) * ldin(w, kk, isbf);
  }
#pragma unroll
  for (int off = 32; off > 0; off >>= 1) sum += __shfl_down(sum, off);
  if (lane == 0) styles[wid] = sum + ldin(ab, r, isbf);
}

// ---------------------------------------------------------------------------
// Modulated+row-normalized weights (fp32) + fp32 biases. grid 3*256, 256 thr.
__global__ void k_weights(const float* __restrict__ styles,
                          const void* __restrict__ wt0, const void* __restrict__ bs0,
                          const void* __restrict__ wt1, const void* __restrict__ bs1,
                          const void* __restrict__ wt2, const void* __restrict__ bs2,
                          float* __restrict__ W0, float* __restrict__ W1,
                          float* __restrict__ W2, float* __restrict__ biasf,
                          const int* __restrict__ flag) {
  int s = blockIdx.x >> 8;
  int o = blockIdx.x & 255;
  int k = threadIdx.x;
  int isbf = flag[0];
  const float* st = styles + s * 5120;
  const void* wt = (s == 0) ? wt0 : (s == 1) ? wt1 : wt2;
  const void* bs = (s == 0) ? bs0 : (s == 1) ? bs1 : bs2;
  float* W = (s == 0) ? W0 : (s == 1) ? W1 : W2;
  float mod = 0.f;
#pragma unroll
  for (int r = 0; r < NRANK; r++)
    mod += st[o * NRANK + r] * st[HCH * NRANK + r * HCH + k];
  mod *= 0.31622776601683794f;  // 1/sqrt(RANK)
  float wv = ldin(wt, o * HCH + k, isbf) * (mod + 1.0f);
  __shared__ float red[HCH];
  red[k] = wv * wv;
  __syncthreads();
  for (int t = 128; t > 0; t >>= 1) {
    if (k < t) red[k] += red[k + t];
    __syncthreads();
  }
  float inv = 1.0f / (sqrtf(red[0]) + 1e-8f);
  W[o * HCH + k] = wv * inv;
  if (k == 0) biasf[s * HCH + o] = ldin(bs, o, isbf);
}

// ---------------------------------------------------------------------------
// M1 = I + cat1_w;  K2 = (I+cat2_w)@nm_w (256x128);
// b23[o] = cat1_b[o] + cat2_b[o] + ((I+cat2_w)@nm_b)[o]
__global__ void k_prep(const void* __restrict__ cat1_w, const void* __restrict__ cat1_b,
                       const void* __restrict__ cat2_w, const void* __restrict__ cat2_b,
                       const void* __restrict__ nm_w, const void* __restrict__ nm_b,
                       float* __restrict__ M1, float* __restrict__ K2,
                       float* __restrict__ b23, const int* __restrict__ flag) {
  int o = blockIdx.x;
  int t = threadIdx.x;
  int isbf = flag[0];
  for (int k = t; k < HCH; k += 128) {
    M1[o * HCH + k] = ldin(cat1_w, o * HCH + k, isbf) + ((k == o) ? 1.f : 0.f);
  }
  float acc = 0.f;
  for (int k = 0; k < HCH; k++) {
    float m2 = ldin(cat2_w, o * HCH + k, isbf) + ((k == o) ? 1.f : 0.f);
    acc += m2 * ldin(nm_w, k * INCH + t, isbf);
  }
  K2[o * INCH + t] = acc;
  if (t == 0) {
    float bb = ldin(cat1_b, o, isbf) + ldin(cat2_b, o, isbf);
    for (int k = 0; k < HCH; k++)
      bb += (ldin(cat2_w, o * HCH + k, isbf) + ((k == o) ? 1.f : 0.f)) * ldin(nm_b, k, isbf);
    b23[o] = bb;
  }
}

// ---------------------------------------------------------------------------
__global__ void k_agg_init(const void* __restrict__ eb, float* __restrict__ agg,
                           int total, const int* __restrict__ flag) {
  int i = blockIdx.x * blockDim.x + threadIdx.x;
  if (i >= total) return;
  agg[i] = ldin(eb, i & (HCH - 1), flag[0]);
}

// one wave per edge; lane handles 4 channels; dst-range filtered (chunking)
__global__ void k_scatter(const int* __restrict__ ei, const void* __restrict__ nw,
                          float* __restrict__ agg, int E, int dstLo, int dstHi,
                          const int* __restrict__ flag) {
  int t = blockIdx.x * blockDim.x + threadIdx.x;
  int e = t >> 6;
  int lane = t & 63;
  if (e >= E) return;
  int dst = ei[E + e];
  if (dst < dstLo || dst >= dstHi) return;
  int src = ei[e];
  int isbf = flag[0];
  size_t base = (size_t)src * HCH + lane * 4;
  float* a = agg + (size_t)(dst - dstLo) * HCH + lane * 4;
  atomicAdd(a + 0, ldin(nw, base + 0, isbf));
  atomicAdd(a + 1, ldin(nw, base + 1, isbf));
  atomicAdd(a + 2, ldin(nw, base + 2, isbf));
  atomicAdd(a + 3, ldin(nw, base + 3, isbf));
}

// ---------------------------------------------------------------------------
// C[m][n] = leaky( A1[m]·B1[n] (+ A2[m]·B2[n]) + bias[n] )
// A1: M x K1 fp32 (ws). A2: raw input (dual dtype), rows offset a2row0.
// B: 256 x K fp32 row-major. Cout: fp32 ws (outdual=0) or d_out (outdual=1,
// dtype per flag). 128x64 tile, 256 threads, 8x4 micro-tile, BK=16.
__global__ __launch_bounds__(256) void k_gemm_f32(
    const float* __restrict__ A1, const float* __restrict__ B1, int K1,
    const void* __restrict__ A2, size_t a2row0, const float* __restrict__ B2, int K2e,
    const float* __restrict__ bias, void* __restrict__ Cout, size_t crow0, int outdual,
    int M, const int* __restrict__ flag) {
  __shared__ float smA[BK][BM + PADA];
  __shared__ float smB[BK][BN + PADB];
  int tid = threadIdx.x;
  int tx = tid & 15;   // m group: rows tx*8..+8
  int ty = tid >> 4;   // n group: cols ty*4..+4
  int bm = blockIdx.x, bn = blockIdx.y;
  int isbf = flag[0];

  float acc[8][4];
#pragma unroll
  for (int i = 0; i < 8; i++)
#pragma unroll
    for (int j = 0; j < 4; j++) acc[i][j] = 0.f;

  int nseg = (A2 != nullptr) ? 2 : 1;
  for (int sg = 0; sg < nseg; sg++) {
    int K = (sg == 0) ? K1 : K2e;
    const float* B = (sg == 0) ? B1 : B2;
    for (int kt = 0; kt < K; kt += BK) {
      // stage A: 128 rows x 16 cols, transposed into smA[k][m]
      {
        int r = tid >> 1, h = tid & 1;
        int gr = bm * BM + r;
        if (gr >= M) gr = M - 1;
        if (sg == 0) {
          const float4* s = (const float4*)(A1 + (size_t)gr * K + kt + h * 8);
          float4 u = s[0], v = s[1];
          smA[h * 8 + 0][r] = u.x; smA[h * 8 + 1][r] = u.y;
          smA[h * 8 + 2][r] = u.z; smA[h * 8 + 3][r] = u.w;
          smA[h * 8 + 4][r] = v.x; smA[h * 8 + 5][r] = v.y;
          smA[h * 8 + 6][r] = v.z; smA[h * 8 + 7][r] = v.w;
        } else {
          size_t base = (a2row0 + gr) * (size_t)K + kt + h * 8;
#pragma unroll
          for (int j = 0; j < 8; j++) smA[h * 8 + j][r] = ldin(A2, base + j, isbf);
        }
      }
      // stage B: 64 rows x 16 cols
      {
        int r = tid >> 2, q = tid & 3;
        const float4 u = *(const float4*)(B + (size_t)(bn * BN + r) * K + kt + q * 4);
        smB[q * 4 + 0][r] = u.x; smB[q * 4 + 1][r] = u.y;
        smB[q * 4 + 2][r] = u.z; smB[q * 4 + 3][r] = u.w;
      }
      __syncthreads();
#pragma unroll
      for (int k = 0; k < BK; k++) {
        float4 a0 = *(const float4*)&smA[k][tx * 8];
        float4 a1 = *(const float4*)&smA[k][tx * 8 + 4];
        float4 b0 = *(const float4*)&smB[k][ty * 4];
        float av[8] = {a0.x, a0.y, a0.z, a0.w, a1.x, a1.y, a1.z, a1.w};
        float bv[4] = {b0.x, b0.y, b0.z, b0.w};
#pragma unroll
        for (int i = 0; i < 8; i++)
#pragma unroll
          for (int j = 0; j < 4; j++) acc[i][j] += av[i] * bv[j];
      }
      __syncthreads();
    }
  }

  int n0 = bn * BN + ty * 4;
  float4 bvv = *(const float4*)&bias[n0];
#pragma unroll
  for (int mi = 0; mi < 8; mi++) {
    int m = bm * BM + tx * 8 + mi;
    if (m >= M) continue;
    float v0 = leaky(acc[mi][0] + bvv.x);
    float v1 = leaky(acc[mi][1] + bvv.y);
    float v2 = leaky(acc[mi][2] + bvv.z);
    float v3 = leaky(acc[mi][3] + bvv.w);
    size_t off = (crow0 + m) * (size_t)HCH + n0;
    if (!outdual || !isbf) {
      float4 v = make_float4(v0, v1, v2, v3);
      *(float4*)((float*)Cout + off) = v;
    } else {
      ushort4 u;
      u.x = f2b(v0); u.y = f2b(v1); u.z = f2b(v2); u.w = f2b(v3);
      *(ushort4*)((ushort*)Cout + off) = u;
    }
  }
}

// ---------------------------------------------------------------------------
extern "C" void kernel_launch(void* const* d_in, const int* in_sizes, int n_in,
                              void* d_out, int out_size, void* d_ws, size_t ws_size,
                              hipStream_t stream) {
  const void* x      = d_in[0];
  const int*  ei     = (const int*)d_in[1];
  const void* w      = d_in[2];
  const void* nw     = d_in[3];
  const void* eb     = d_in[4];
  const void* le_aw  = d_in[5];
  const void* le_ab  = d_in[6];
  const void* le_w   = d_in[7];
  const void* le_b   = d_in[8];
  const void* cat1_w = d_in[10];
  const void* cat1_b = d_in[11];
  const void* cat2_w = d_in[12];
  const void* cat2_b = d_in[13];
  const void* nm_w   = d_in[14];
  const void* nm_b   = d_in[15];
  const void* f1_aw  = d_in[16];
  const void* f1_ab  = d_in[17];
  const void* f1_w   = d_in[18];
  const void* f1_b   = d_in[19];
  const void* f2_aw  = d_in[21];
  const void* f2_ab  = d_in[22];
  const void* f2_w   = d_in[23];
  const void* f2_b   = d_in[24];

  const int N = in_sizes[3] / HCH;  // 50000
  const int E = in_sizes[1] / 2;    // 800000

  uint8_t* ws = (uint8_t*)d_ws;
  int*   flag   = (int*)(ws + 0);
  float* styles = (float*)(ws + 1024);      // 15360 f32 -> ends 62464
  float* biasf  = (float*)(ws + 65536);     // 768 f32
  float* b23    = (float*)(ws + 69632);     // 256 f32
  float* Wle    = (float*)(ws + 131072);    // 256x256 f32
  float* Wf1    = (float*)(ws + 393216);
  float* Wf2    = (float*)(ws + 655360);
  float* M1     = (float*)(ws + 917504);
  float* K2f    = (float*)(ws + 1179648);   // 256x128 f32 -> ends 1310720
  const int cn = (N + 3) / 4;               // chunk rows
  float* big0   = (float*)(ws + 2097152);                       // cn*256 f32
  float* big1   = (float*)(ws + 2097152 + (size_t)cn * 1024);   // cn*256 f32
  // total ws use: 2 MB + 2*cn*1024 B  (~27.7 MB for N=50000)

  k_detect<<<1, 1, 0, stream>>>(w, flag);
  k_styles<<<3840, 256, 0, stream>>>(le_aw, le_ab, f1_aw, f1_ab, f2_aw, f2_ab, w,
                                     styles, flag);
  k_weights<<<768, 256, 0, stream>>>(styles, le_w, le_b, f1_w, f1_b, f2_w, f2_b,
                                     Wle, Wf1, Wf2, biasf, flag);
  k_prep<<<256, 128, 0, stream>>>(cat1_w, cat1_b, cat2_w, cat2_b, nm_w, nm_b,
                                  M1, K2f, b23, flag);

  int sblocks = (E * 64 + 255) / 256;
  for (int c = 0; c < 4; c++) {
    int r0 = c * cn;
    int Mc = N - r0;
    if (Mc > cn) Mc = cn;
    if (Mc <= 0) continue;
    int tot = Mc * HCH;
    k_agg_init<<<(tot + 255) / 256, 256, 0, stream>>>(eb, big0, tot, flag);
    k_scatter<<<sblocks, 256, 0, stream>>>(ei, nw, big0, E, r0, r0 + Mc, flag);
    dim3 g((Mc + BM - 1) / BM, HCH / BN);
    k_gemm_f32<<<g, 256, 0, stream>>>(big0, Wle, HCH, nullptr, 0, nullptr, 0,
                                      biasf + 0, big1, 0, 0, Mc, flag);
    k_gemm_f32<<<g, 256, 0, stream>>>(big1, M1, HCH, x, (size_t)r0, K2f, INCH,
                                      b23, big0, 0, 0, Mc, flag);
    k_gemm_f32<<<g, 256, 0, stream>>>(big0, Wf1, HCH, nullptr, 0, nullptr, 0,
                                      biasf + HCH, big1, 0, 0, Mc, flag);
    k_gemm_f32<<<g, 256, 0, stream>>>(big1, Wf2, HCH, nullptr, 0, nullptr, 0,
                                      biasf + 2 * HCH, d_out, (size_t)r0, 1, Mc, flag);
  }
}

// Round 5
// 841.870 us; speedup vs baseline: 4.2441x; 4.2441x over previous
//
#include <hip/hip_runtime.h>
#include <stdint.h>

#define HCH 256     // H
#define INCH 128    // IN
#define WDIM 512    // WD
#define NRANK 10
#define SLOPE 0.01f

#define GBM 128
#define GBN 128
#define GBK 16
#define GPAD 4

__device__ __forceinline__ float leaky(float v) { return v >= 0.f ? v : SLOPE * v; }

// ---------------------------------------------------------------------------
// styles[s*5120 + r] = dot(aw_s[r,:512], w) + ab_s[r]   (one wave per row)
__global__ void k_styles(const float* __restrict__ aw0, const float* __restrict__ ab0,
                         const float* __restrict__ aw1, const float* __restrict__ ab1,
                         const float* __restrict__ aw2, const float* __restrict__ ab2,
                         const float* __restrict__ w, float* __restrict__ styles) {
  int wid = blockIdx.x * 4 + (threadIdx.x >> 6);   // 15360 waves
  int lane = threadIdx.x & 63;
  int s = wid / 5120;
  int r = wid - s * 5120;
  const float* aw = (s == 0) ? aw0 : (s == 1) ? aw1 : aw2;
  const float* ab = (s == 0) ? ab0 : (s == 1) ? ab1 : ab2;
  const float4* ap = (const float4*)(aw + (size_t)r * WDIM + lane * 8);
  const float4* wp = (const float4*)(w + lane * 8);
  float4 a0 = ap[0], a1 = ap[1], w0 = wp[0], w1 = wp[1];
  float sum = a0.x * w0.x + a0.y * w0.y + a0.z * w0.z + a0.w * w0.w +
              a1.x * w1.x + a1.y * w1.y + a1.z * w1.z + a1.w * w1.w;
#pragma unroll
  for (int off = 32; off > 0; off >>= 1) sum += __shfl_down(sum, off);
  if (lane == 0) styles[wid] = sum + ab[r];
}

// ---------------------------------------------------------------------------
// Modulated + row-normalized weights + biases. grid 3*256, 256 thr.
__global__ void k_weights(const float* __restrict__ styles,
                          const float* __restrict__ wt0, const float* __restrict__ bs0,
                          const float* __restrict__ wt1, const float* __restrict__ bs1,
                          const float* __restrict__ wt2, const float* __restrict__ bs2,
                          float* __restrict__ W0, float* __restrict__ W1,
                          float* __restrict__ W2, float* __restrict__ biasf) {
  int s = blockIdx.x >> 8;
  int o = blockIdx.x & 255;
  int k = threadIdx.x;
  const float* st = styles + s * 5120;
  const float* wt = (s == 0) ? wt0 : (s == 1) ? wt1 : wt2;
  const float* bs = (s == 0) ? bs0 : (s == 1) ? bs1 : bs2;
  float* W = (s == 0) ? W0 : (s == 1) ? W1 : W2;
  float mod = 0.f;
#pragma unroll
  for (int r = 0; r < NRANK; r++)
    mod += st[o * NRANK + r] * st[HCH * NRANK + r * HCH + k];
  mod *= 0.31622776601683794f;  // 1/sqrt(RANK)
  float wv = wt[o * HCH + k] * (mod + 1.0f);
  __shared__ float red[HCH];
  red[k] = wv * wv;
  __syncthreads();
  for (int t = 128; t > 0; t >>= 1) {
    if (k < t) red[k] += red[k + t];
    __syncthreads();
  }
  float inv = 1.0f / (sqrtf(red[0]) + 1e-8f);
  W[o * HCH + k] = wv * inv;
  if (k == 0) biasf[s * HCH + o] = bs[o];
}

// ---------------------------------------------------------------------------
// M1 = I + cat1_w;  K2 = (I+cat2_w)@nm_w (256x128);
// b23[o] = cat1_b[o] + cat2_b[o] + ((I+cat2_w)@nm_b)[o]
__global__ void k_prep(const float* __restrict__ cat1_w, const float* __restrict__ cat1_b,
                       const float* __restrict__ cat2_w, const float* __restrict__ cat2_b,
                       const float* __restrict__ nm_w, const float* __restrict__ nm_b,
                       float* __restrict__ M1, float* __restrict__ K2,
                       float* __restrict__ b23) {
  int o = blockIdx.x;
  int t = threadIdx.x;
  for (int k = t; k < HCH; k += 128)
    M1[o * HCH + k] = cat1_w[o * HCH + k] + ((k == o) ? 1.f : 0.f);
  float acc = 0.f;
  for (int k = 0; k < HCH; k++) {
    float m2 = cat2_w[o * HCH + k] + ((k == o) ? 1.f : 0.f);
    acc += m2 * nm_w[k * INCH + t];
  }
  K2[o * INCH + t] = acc;
  if (t == 0) {
    float bb = cat1_b[o] + cat2_b[o];
    for (int k = 0; k < HCH; k++)
      bb += (cat2_w[o * HCH + k] + ((k == o) ? 1.f : 0.f)) * nm_b[k];
    b23[o] = bb;
  }
}

// ---------------------------------------------------------------------------
// CSR build
__global__ void k_zero(int* __restrict__ p, int n) {
  int i = blockIdx.x * blockDim.x + threadIdx.x;
  if (i < n) p[i] = 0;
}
__global__ void k_hist(const int* __restrict__ ei, int* __restrict__ cnt, int E) {
  int e = blockIdx.x * blockDim.x + threadIdx.x;
  if (e < E) atomicAdd(&cnt[ei[E + e]], 1);
}
__global__ void k_bsum(const int* __restrict__ cnt, int* __restrict__ bsum, int N) {
  __shared__ int red[256];
  int t = threadIdx.x;
  int i = blockIdx.x * 256 + t;
  red[t] = (i < N) ? cnt[i] : 0;
  __syncthreads();
  for (int d = 128; d > 0; d >>= 1) {
    if (t < d) red[t] += red[t + d];
    __syncthreads();
  }
  if (t == 0) bsum[blockIdx.x] = red[0];
}
__global__ void k_scanb(int* __restrict__ bsum, int* __restrict__ offsets, int NB,
                        int N, int E) {
  if (threadIdx.x == 0) {
    int run = 0;
    for (int b = 0; b < NB; b++) { int v = bsum[b]; bsum[b] = run; run += v; }
    offsets[N] = E;
  }
}
__global__ void k_scanseg(int* __restrict__ cnt, const int* __restrict__ bsum,
                          int* __restrict__ offsets, int N) {
  __shared__ int s[256];
  int t = threadIdx.x;
  int i = blockIdx.x * 256 + t;
  int v = (i < N) ? cnt[i] : 0;
  s[t] = v;
  __syncthreads();
  for (int d = 1; d < 256; d <<= 1) {
    int tv = (t >= d) ? s[t - d] : 0;
    __syncthreads();
    s[t] += tv;
    __syncthreads();
  }
  if (i < N) {
    offsets[i] = bsum[blockIdx.x] + s[t] - v;  // exclusive
    cnt[i] = 0;                                // becomes placement cursor
  }
}
__global__ void k_place(const int* __restrict__ ei, const int* __restrict__ offsets,
                        int* __restrict__ cur, int* __restrict__ csr, int E) {
  int e = blockIdx.x * blockDim.x + threadIdx.x;
  if (e >= E) return;
  int dst = ei[E + e];
  int pos = atomicAdd(&cur[dst], 1);
  csr[offsets[dst] + pos] = ei[e];
}

// ---------------------------------------------------------------------------
// Pull aggregation: one wave per node; lane owns 4 channels.
__global__ void k_pull(const int* __restrict__ csr, const int* __restrict__ offsets,
                       const float* __restrict__ nw, const float* __restrict__ eb,
                       float* __restrict__ agg, int r0, int Mc) {
  int wid = blockIdx.x * 4 + (threadIdx.x >> 6);
  if (wid >= Mc) return;
  int lane = threadIdx.x & 63;
  int node = r0 + wid;
  int s0 = offsets[node], s1 = offsets[node + 1];
  float4 acc = *(const float4*)(eb + lane * 4);
  float4 acc2 = make_float4(0.f, 0.f, 0.f, 0.f);
  int j = s0;
  for (; j + 1 < s1; j += 2) {
    int sa = csr[j], sb = csr[j + 1];
    float4 va = *(const float4*)(nw + (size_t)sa * HCH + lane * 4);
    float4 vb = *(const float4*)(nw + (size_t)sb * HCH + lane * 4);
    acc.x += va.x; acc.y += va.y; acc.z += va.z; acc.w += va.w;
    acc2.x += vb.x; acc2.y += vb.y; acc2.z += vb.z; acc2.w += vb.w;
  }
  if (j < s1) {
    int sa = csr[j];
    float4 va = *(const float4*)(nw + (size_t)sa * HCH + lane * 4);
    acc.x += va.x; acc.y += va.y; acc.z += va.z; acc.w += va.w;
  }
  acc.x += acc2.x; acc.y += acc2.y; acc.z += acc2.z; acc.w += acc2.w;
  *(float4*)(agg + (size_t)wid * HCH + lane * 4) = acc;
}

// ---------------------------------------------------------------------------
// C[m][n] = leaky( A1[m]·B1[n] (+ A2[m]·B2[n]) + bias[n] ), all fp32.
// 128x128 tile, 256 threads, 8x8 micro-tile, BK=16, transposed LDS staging.
__global__ __launch_bounds__(256) void k_gemm_f32(
    const float* __restrict__ A1, const float* __restrict__ B1, int K1,
    const float* __restrict__ A2, size_t a2row0, const float* __restrict__ B2, int K2e,
    const float* __restrict__ bias, float* __restrict__ Cout, size_t crow0, int M) {
  __shared__ float smA[GBK][GBM + GPAD];
  __shared__ float smB[GBK][GBN + GPAD];
  int tid = threadIdx.x;
  int tx = tid & 15;   // m group: rows tx*8..+8
  int ty = tid >> 4;   // n group: cols ty*8..+8
  int bm = blockIdx.x, bn = blockIdx.y;

  float acc[8][8];
#pragma unroll
  for (int i = 0; i < 8; i++)
#pragma unroll
    for (int j = 0; j < 8; j++) acc[i][j] = 0.f;

  int nseg = (A2 != nullptr) ? 2 : 1;
  int r = tid >> 1, h = tid & 1;
  for (int sg = 0; sg < nseg; sg++) {
    int K = (sg == 0) ? K1 : K2e;
    const float* B = (sg == 0) ? B1 : B2;
    int gr = bm * GBM + r;
    if (gr >= M) gr = M - 1;
    const float* Arow = (sg == 0) ? (A1 + (size_t)gr * K)
                                  : (A2 + (a2row0 + (size_t)gr) * K);
    const float* Brow = B + (size_t)(bn * GBN + r) * K;  // B has 256 valid rows
    for (int kt = 0; kt < K; kt += GBK) {
      float4 u = *(const float4*)(Arow + kt + h * 8);
      float4 v = *(const float4*)(Arow + kt + h * 8 + 4);
      smA[h * 8 + 0][r] = u.x; smA[h * 8 + 1][r] = u.y;
      smA[h * 8 + 2][r] = u.z; smA[h * 8 + 3][r] = u.w;
      smA[h * 8 + 4][r] = v.x; smA[h * 8 + 5][r] = v.y;
      smA[h * 8 + 6][r] = v.z; smA[h * 8 + 7][r] = v.w;
      float4 p = *(const float4*)(Brow + kt + h * 8);
      float4 q = *(const float4*)(Brow + kt + h * 8 + 4);
      smB[h * 8 + 0][r] = p.x; smB[h * 8 + 1][r] = p.y;
      smB[h * 8 + 2][r] = p.z; smB[h * 8 + 3][r] = p.w;
      smB[h * 8 + 4][r] = q.x; smB[h * 8 + 5][r] = q.y;
      smB[h * 8 + 6][r] = q.z; smB[h * 8 + 7][r] = q.w;
      __syncthreads();
#pragma unroll
      for (int k = 0; k < GBK; k++) {
        float4 a0 = *(const float4*)&smA[k][tx * 8];
        float4 a1 = *(const float4*)&smA[k][tx * 8 + 4];
        float4 b0 = *(const float4*)&smB[k][ty * 8];
        float4 b1 = *(const float4*)&smB[k][ty * 8 + 4];
        float av[8] = {a0.x, a0.y, a0.z, a0.w, a1.x, a1.y, a1.z, a1.w};
        float bv[8] = {b0.x, b0.y, b0.z, b0.w, b1.x, b1.y, b1.z, b1.w};
#pragma unroll
        for (int i = 0; i < 8; i++)
#pragma unroll
          for (int j = 0; j < 8; j++) acc[i][j] += av[i] * bv[j];
      }
      __syncthreads();
    }
  }

  int n0 = bn * GBN + ty * 8;
  float4 bv0 = *(const float4*)&bias[n0];
  float4 bv1 = *(const float4*)&bias[n0 + 4];
#pragma unroll
  for (int mi = 0; mi < 8; mi++) {
    int m = bm * GBM + tx * 8 + mi;
    if (m >= M) continue;
    float4 o0, o1;
    o0.x = leaky(acc[mi][0] + bv0.x); o0.y = leaky(acc[mi][1] + bv0.y);
    o0.z = leaky(acc[mi][2] + bv0.z); o0.w = leaky(acc[mi][3] + bv0.w);
    o1.x = leaky(acc[mi][4] + bv1.x); o1.y = leaky(acc[mi][5] + bv1.y);
    o1.z = leaky(acc[mi][6] + bv1.z); o1.w = leaky(acc[mi][7] + bv1.w);
    float* cp = Cout + (crow0 + (size_t)m) * HCH + n0;
    *(float4*)cp = o0;
    *(float4*)(cp + 4) = o1;
  }
}

// ---------------------------------------------------------------------------
extern "C" void kernel_launch(void* const* d_in, const int* in_sizes, int n_in,
                              void* d_out, int out_size, void* d_ws, size_t ws_size,
                              hipStream_t stream) {
  const float* x      = (const float*)d_in[0];
  const int*   ei     = (const int*)d_in[1];
  const float* w      = (const float*)d_in[2];
  const float* nw     = (const float*)d_in[3];
  const float* eb     = (const float*)d_in[4];
  const float* le_aw  = (const float*)d_in[5];
  const float* le_ab  = (const float*)d_in[6];
  const float* le_w   = (const float*)d_in[7];
  const float* le_b   = (const float*)d_in[8];
  const float* cat1_w = (const float*)d_in[10];
  const float* cat1_b = (const float*)d_in[11];
  const float* cat2_w = (const float*)d_in[12];
  const float* cat2_b = (const float*)d_in[13];
  const float* nm_w   = (const float*)d_in[14];
  const float* nm_b   = (const float*)d_in[15];
  const float* f1_aw  = (const float*)d_in[16];
  const float* f1_ab  = (const float*)d_in[17];
  const float* f1_w   = (const float*)d_in[18];
  const float* f1_b   = (const float*)d_in[19];
  const float* f2_aw  = (const float*)d_in[21];
  const float* f2_ab  = (const float*)d_in[22];
  const float* f2_w   = (const float*)d_in[23];
  const float* f2_b   = (const float*)d_in[24];

  const int N = in_sizes[3] / HCH;  // 50000
  const int E = in_sizes[1] / 2;    // 800000
  const int NB = (N + 255) / 256;

  uint8_t* ws = (uint8_t*)d_ws;
  float* styles  = (float*)(ws + 1024);      // 15360 f32
  float* biasf   = (float*)(ws + 65536);     // 768 f32
  float* b23     = (float*)(ws + 69632);     // 256 f32
  float* Wle     = (float*)(ws + 131072);    // 256x256 f32
  float* Wf1     = (float*)(ws + 393216);
  float* Wf2     = (float*)(ws + 655360);
  float* M1      = (float*)(ws + 917504);
  float* K2f     = (float*)(ws + 1179648);   // 256x128 f32 -> ends 1310720
  int*   cnt     = (int*)(ws + 1376256);     // N ints
  int*   bsum    = (int*)(ws + 1376256 + 262144);              // NB ints
  int*   offsets = (int*)(ws + 1376256 + 262144 + 4096);       // N+1 ints
  int*   csr     = (int*)(ws + 1376256 + 262144 + 4096 + 262144);  // E ints
  size_t bigoff  = 1376256 + 262144 + 4096 + 262144 + (size_t)E * 4 + 65536;
  bigoff = (bigoff + 1023) & ~(size_t)1023;

  // Adaptive chunk size from actual workspace budget.
  size_t avail = (ws_size > bigoff + 2048 * 1024) ? (ws_size - bigoff) : (2048 * 1024);
  long long cnl = (long long)(avail / (2 * HCH * sizeof(float)));
  int cn = (cnl > N) ? N : (int)cnl;
  if (cn < 1024) cn = 1024;
  int nchunks = (N + cn - 1) / cn;
  float* big0 = (float*)(ws + bigoff);
  float* big1 = big0 + (size_t)cn * HCH;

  // Small prep
  k_styles<<<3840, 256, 0, stream>>>(le_aw, le_ab, f1_aw, f1_ab, f2_aw, f2_ab, w, styles);
  k_weights<<<768, 256, 0, stream>>>(styles, le_w, le_b, f1_w, f1_b, f2_w, f2_b,
                                     Wle, Wf1, Wf2, biasf);
  k_prep<<<256, 128, 0, stream>>>(cat1_w, cat1_b, cat2_w, cat2_b, nm_w, nm_b, M1, K2f, b23);

  // CSR build
  int eb256 = (E + 255) / 256;
  k_zero<<<NB, 256, 0, stream>>>(cnt, N);
  k_hist<<<eb256, 256, 0, stream>>>(ei, cnt, E);
  k_bsum<<<NB, 256, 0, stream>>>(cnt, bsum, N);
  k_scanb<<<1, 64, 0, stream>>>(bsum, offsets, NB, N, E);
  k_scanseg<<<NB, 256, 0, stream>>>(cnt, bsum, offsets, N);
  k_place<<<eb256, 256, 0, stream>>>(ei, offsets, cnt, csr, E);

  for (int c = 0; c < nchunks; c++) {
    int r0 = c * cn;
    int Mc = N - r0;
    if (Mc > cn) Mc = cn;
    if (Mc <= 0) continue;
    k_pull<<<(Mc + 3) / 4, 256, 0, stream>>>(csr, offsets, nw, eb, big0, r0, Mc);
    dim3 g((Mc + GBM - 1) / GBM, HCH / GBN);
    k_gemm_f32<<<g, 256, 0, stream>>>(big0, Wle, HCH, nullptr, 0, nullptr, 0,
                                      biasf + 0, big1, 0, Mc);
    k_gemm_f32<<<g, 256, 0, stream>>>(big1, M1, HCH, x, (size_t)r0, K2f, INCH,
                                      b23, big0, 0, Mc);
    k_gemm_f32<<<g, 256, 0, stream>>>(big0, Wf1, HCH, nullptr, 0, nullptr, 0,
                                      biasf + HCH, big1, 0, Mc);
    k_gemm_f32<<<g, 256, 0, stream>>>(big1, Wf2, HCH, nullptr, 0, nullptr, 0,
                                      biasf + 2 * HCH, (float*)d_out, (size_t)r0, Mc);
  }
}